// Round 9
// baseline (401.767 us; speedup 1.0000x reference)
//
#include <hip/hip_runtime.h>
#include <math.h>

#define IN_C 128
#define HID 32
#define HEADS 4
#define OUT_C 128
#define NEG_SLOPE 0.2f

typedef float v2f __attribute__((ext_vector_type(2)));
typedef unsigned int uint_t;
typedef unsigned short ushort_t;

// f32 -> bf16 round-to-nearest-even
__device__ __forceinline__ ushort_t f2bf(float f) {
    uint_t u = __float_as_uint(f);
    u = (u + 0x7fffu + ((u >> 16) & 1u)) >> 16;
    return (ushort_t)u;
}
// one uint = 2 bf16 channels -> 2 floats (low ushort = lower channel)
__device__ __forceinline__ float2 bf2f2(uint_t u) {
    float2 r;
    r.x = __uint_as_float(u << 16);
    r.y = __uint_as_float(u & 0xffff0000u);
    return r;
}

// ---------- dual transform: outl(bf16) = x@Wl, outr(f32) = x@Wr ----------
// TROWS=32, register double-buffered W loads: fetch k0+4's 8 W values before
// computing k0's 64 pk_fma -> W latency hidden behind FMA issue.
#define TROWS 32
__global__ __launch_bounds__(256) void transform_dual(
        const float* __restrict__ x,
        const float* __restrict__ Wl,
        const float* __restrict__ Wr,
        ushort_t* __restrict__ outl,
        float* __restrict__ outr, int n) {
    __shared__ float xs[TROWS][IN_C];
    const int col = threadIdx.x & 127;
    const int rh  = threadIdx.x >> 7;        // 0 or 1 -> rows rh*16..rh*16+15
    const int row0 = blockIdx.x * TROWS;
    // stage x tile: thread t loads rows (t>>5) + 8*pass, cols (t&31)*4 (float4)
    {
        const int lr = threadIdx.x >> 5;     // 0..7
        const int lc = (threadIdx.x & 31) * 4;
#pragma unroll
        for (int pass = 0; pass < 4; ++pass) {
            int r = pass * 8 + lr;
            int row = row0 + r;
            float4 v = make_float4(0.f, 0.f, 0.f, 0.f);
            if (row < n) v = *(const float4*)&x[(size_t)row * IN_C + lc];
            *(float4*)&xs[r][lc] = v;
        }
    }
    __syncthreads();
    v2f acc[16];
#pragma unroll
    for (int r = 0; r < 16; ++r) acc[r] = (v2f){0.f, 0.f};
    v2f wbuf[2][4];
    // preload k0 = 0
#pragma unroll
    for (int q = 0; q < 4; ++q) {
        wbuf[0][q][0] = Wl[q * IN_C + col];
        wbuf[0][q][1] = Wr[q * IN_C + col];
    }
    for (int k0 = 0; k0 < IN_C; k0 += 4) {
        const int cur = (k0 >> 2) & 1;
        if (k0 + 4 < IN_C) {
#pragma unroll
            for (int q = 0; q < 4; ++q) {
                wbuf[cur ^ 1][q][0] = Wl[(k0 + 4 + q) * IN_C + col];
                wbuf[cur ^ 1][q][1] = Wr[(k0 + 4 + q) * IN_C + col];
            }
        }
#pragma unroll
        for (int r = 0; r < 16; ++r) {
            float4 xv = *(const float4*)&xs[rh * 16 + r][k0];   // b128 broadcast
            acc[r] = __builtin_elementwise_fma((v2f){xv.x, xv.x}, wbuf[cur][0], acc[r]);
            acc[r] = __builtin_elementwise_fma((v2f){xv.y, xv.y}, wbuf[cur][1], acc[r]);
            acc[r] = __builtin_elementwise_fma((v2f){xv.z, xv.z}, wbuf[cur][2], acc[r]);
            acc[r] = __builtin_elementwise_fma((v2f){xv.w, xv.w}, wbuf[cur][3], acc[r]);
        }
    }
#pragma unroll
    for (int r = 0; r < 16; ++r) {
        int row = row0 + rh * 16 + r;
        if (row < n) {
            outl[(size_t)row * IN_C + col] = f2bf(acc[r][0]);
            outr[(size_t)row * IN_C + col] = acc[r][1];
        }
    }
}

// ---------- CSR build ----------
__global__ void hist_kernel(const int* __restrict__ dst, int* __restrict__ cnt, int E) {
    int e = blockIdx.x * blockDim.x + threadIdx.x;
    if (e < E) atomicAdd(&cnt[dst[e]], 1);
}

__global__ void scan_block_sums(const int* __restrict__ cnt, int* __restrict__ part, int n) {
    __shared__ int sdata[256];
    int t = threadIdx.x;
    int i = blockIdx.x * 256 + t;
    sdata[t] = (i < n) ? cnt[i] : 0;
    __syncthreads();
    for (int o = 128; o >= 1; o >>= 1) {
        if (t < o) sdata[t] += sdata[t + o];
        __syncthreads();
    }
    if (t == 0) part[blockIdx.x] = sdata[0];
}

__global__ void scan_part_excl(int* __restrict__ part, int nb) {  // single block
    __shared__ int buf[1024];
    int t = threadIdx.x;
    int v = (t < nb) ? part[t] : 0;
    buf[t] = v;
    __syncthreads();
    for (int o = 1; o < 1024; o <<= 1) {
        int a = (t >= o) ? buf[t - o] : 0;
        __syncthreads();
        buf[t] += a;
        __syncthreads();
    }
    if (t < nb) part[t] = buf[t] - v;   // exclusive
}

__global__ void scan_final(const int* __restrict__ cnt, const int* __restrict__ part,
                           int* __restrict__ rowptr, int n) {
    __shared__ int buf[256];
    int t = threadIdx.x;
    int i = blockIdx.x * 256 + t;
    int v = (i < n) ? cnt[i] : 0;
    buf[t] = v;
    __syncthreads();
    for (int o = 1; o < 256; o <<= 1) {
        int a = (t >= o) ? buf[t - o] : 0;
        __syncthreads();
        buf[t] += a;
        __syncthreads();
    }
    int excl = part[blockIdx.x] + buf[t] - v;
    if (i < n) rowptr[i] = excl;
    if (i == n - 1) rowptr[n] = excl + v;
}

__global__ void scatter_csr(const int* __restrict__ src,
                            const int* __restrict__ dst,
                            const int* __restrict__ rowptr,
                            int* __restrict__ cursor,
                            int* __restrict__ gsrc, int E) {
    int e = blockIdx.x * blockDim.x + threadIdx.x;
    if (e >= E) return;
    int d = dst[e];
    int pos = atomicAdd(&cursor[d], 1);
    gsrc[rowptr[d] + pos] = src[e];
}

// ---------- fused kernels: 16-lane group per edge, 4 edges/wave ----------
// BRANCH-FREE chunk loop; loads batched (4 gsrc, then 4 rows).

// layer 1: 4 heads x 32ch; head of lane = q>>2; reduce within 4 lanes.
__global__ __launch_bounds__(256) void node_fused1(
        const ushort_t* __restrict__ xlb,
        const float* __restrict__ xr,
        const float* __restrict__ att,
        const int* __restrict__ rowptr,
        const int* __restrict__ gsrc,
        const float* __restrict__ b,
        float* __restrict__ hout, int N) {
    const int wv = threadIdx.x >> 6;
    const int l  = threadIdx.x & 63;
    const int g  = l >> 4, q = l & 15;
    const int d  = blockIdx.x * 4 + wv;
    if (d >= N) return;
    const int beg = rowptr[d], end = rowptr[d + 1];
    const int cb = q * 8;
    const float4 xra = *(const float4*)&xr[(size_t)d * IN_C + cb];
    const float4 xrb = *(const float4*)&xr[(size_t)d * IN_C + cb + 4];
    float4 a6a = *(const float4*)&att[cb];
    float4 a6b = *(const float4*)&att[cb + 4];
    float4 a4a, a4b;
    a4a.x = 0.4f * a6a.x; a4a.y = 0.4f * a6a.y; a4a.z = 0.4f * a6a.z; a4a.w = 0.4f * a6a.w;
    a4b.x = 0.4f * a6b.x; a4b.y = 0.4f * a6b.y; a4b.z = 0.4f * a6b.z; a4b.w = 0.4f * a6b.w;
    a6a.x *= 0.6f; a6a.y *= 0.6f; a6a.z *= 0.6f; a6a.w *= 0.6f;
    a6b.x *= 0.6f; a6b.y *= 0.6f; a6b.z *= 0.6f; a6b.w *= 0.6f;
    float m = -1e30f, ls = 0.f;
    float4 acca = {0.f,0.f,0.f,0.f}, accb = {0.f,0.f,0.f,0.f};
    for (int c0 = beg; c0 < end; c0 += 16) {
        // phase a: 4 independent gsrc loads (clamped)
        int sA[4];
#pragma unroll
        for (int u = 0; u < 4; ++u) {
            int j = c0 + 4 * u + g;
            sA[u] = gsrc[min(j, end - 1)];
        }
        // phase b: 4 independent row loads
        uint4 w[4];
#pragma unroll
        for (int u = 0; u < 4; ++u)
            w[u] = *(const uint4*)&xlb[(size_t)sA[u] * IN_C + cb];
        // phase c: unpack + score + mask
        float f[4];
        float4 va[4], vb[4];
#pragma unroll
        for (int u = 0; u < 4; ++u) {
            float2 c01 = bf2f2(w[u].x), c23 = bf2f2(w[u].y);
            float2 c45 = bf2f2(w[u].z), c67 = bf2f2(w[u].w);
            va[u] = make_float4(c01.x, c01.y, c23.x, c23.y);
            vb[u] = make_float4(c45.x, c45.y, c67.x, c67.y);
            float p = 0.f, t;
            t = va[u].x + xra.x; p = fmaf(a6a.x, t, fmaf(a4a.x, fabsf(t), p));
            t = va[u].y + xra.y; p = fmaf(a6a.y, t, fmaf(a4a.y, fabsf(t), p));
            t = va[u].z + xra.z; p = fmaf(a6a.z, t, fmaf(a4a.z, fabsf(t), p));
            t = va[u].w + xra.w; p = fmaf(a6a.w, t, fmaf(a4a.w, fabsf(t), p));
            t = vb[u].x + xrb.x; p = fmaf(a6b.x, t, fmaf(a4b.x, fabsf(t), p));
            t = vb[u].y + xrb.y; p = fmaf(a6b.y, t, fmaf(a4b.y, fabsf(t), p));
            t = vb[u].z + xrb.z; p = fmaf(a6b.z, t, fmaf(a4b.z, fabsf(t), p));
            t = vb[u].w + xrb.w; p = fmaf(a6b.w, t, fmaf(a4b.w, fabsf(t), p));
            // per-head reduce: 4-lane subgroup (head = q>>2)
            p += __shfl_xor(p, 1, 64);
            p += __shfl_xor(p, 2, 64);
            f[u] = (c0 + 4 * u + g < end) ? p : -1e30f;
        }
        float bm = fmaxf(fmaxf(f[0], f[1]), fmaxf(f[2], f[3]));
        float nm = fmaxf(m, bm);
        float fc = __expf(m - nm);
        ls *= fc;
        acca.x *= fc; acca.y *= fc; acca.z *= fc; acca.w *= fc;
        accb.x *= fc; accb.y *= fc; accb.z *= fc; accb.w *= fc;
#pragma unroll
        for (int u = 0; u < 4; ++u) {
            float wgt = __expf(f[u] - nm);
            ls += wgt;
            acca.x = fmaf(wgt, va[u].x, acca.x);
            acca.y = fmaf(wgt, va[u].y, acca.y);
            acca.z = fmaf(wgt, va[u].z, acca.z);
            acca.w = fmaf(wgt, va[u].w, acca.w);
            accb.x = fmaf(wgt, vb[u].x, accb.x);
            accb.y = fmaf(wgt, vb[u].y, accb.y);
            accb.z = fmaf(wgt, vb[u].z, accb.z);
            accb.w = fmaf(wgt, vb[u].w, accb.w);
        }
        m = nm;
    }
    // merge 4 groups (xor 16/32 partners share q -> same head)
#pragma unroll
    for (int o = 16; o <= 32; o <<= 1) {
        float mo = __shfl_xor(m, o, 64);
        float lo = __shfl_xor(ls, o, 64);
        float ax = __shfl_xor(acca.x, o, 64), ay = __shfl_xor(acca.y, o, 64);
        float az = __shfl_xor(acca.z, o, 64), aw = __shfl_xor(acca.w, o, 64);
        float bx = __shfl_xor(accb.x, o, 64), by = __shfl_xor(accb.y, o, 64);
        float bz = __shfl_xor(accb.z, o, 64), bw = __shfl_xor(accb.w, o, 64);
        float nm = fmaxf(m, mo);
        float fs = __expf(m - nm), fo = __expf(mo - nm);
        ls = ls * fs + lo * fo;
        acca.x = acca.x * fs + ax * fo; acca.y = acca.y * fs + ay * fo;
        acca.z = acca.z * fs + az * fo; acca.w = acca.w * fs + aw * fo;
        accb.x = accb.x * fs + bx * fo; accb.y = accb.y * fs + by * fo;
        accb.z = accb.z * fs + bz * fo; accb.w = accb.w * fs + bw * fo;
        m = nm;
    }
    if (g == 0) {
        float inv = (ls > 0.f) ? 1.f / ls : 0.f;
        const float4 b4a = *(const float4*)&b[cb];
        const float4 b4b = *(const float4*)&b[cb + 4];
        float4 o1, o2;
        o1.x = acca.x * inv + b4a.x; o1.y = acca.y * inv + b4a.y;
        o1.z = acca.z * inv + b4a.z; o1.w = acca.w * inv + b4a.w;
        o2.x = accb.x * inv + b4b.x; o2.y = accb.y * inv + b4b.y;
        o2.z = accb.z * inv + b4b.z; o2.w = accb.w * inv + b4b.w;
        o1.x = (o1.x > 0.f) ? o1.x : expm1f(o1.x);
        o1.y = (o1.y > 0.f) ? o1.y : expm1f(o1.y);
        o1.z = (o1.z > 0.f) ? o1.z : expm1f(o1.z);
        o1.w = (o1.w > 0.f) ? o1.w : expm1f(o1.w);
        o2.x = (o2.x > 0.f) ? o2.x : expm1f(o2.x);
        o2.y = (o2.y > 0.f) ? o2.y : expm1f(o2.y);
        o2.z = (o2.z > 0.f) ? o2.z : expm1f(o2.z);
        o2.w = (o2.w > 0.f) ? o2.w : expm1f(o2.w);
        *(float4*)&hout[(size_t)d * IN_C + cb]     = o1;
        *(float4*)&hout[(size_t)d * IN_C + cb + 4] = o2;
    }
}

// layer 2: single head x 128ch; reduce within all 16 lanes of the group.
__global__ __launch_bounds__(256) void node_fused2(
        const ushort_t* __restrict__ xlb,
        const float* __restrict__ xr,
        const float* __restrict__ att,
        const int* __restrict__ rowptr,
        const int* __restrict__ gsrc,
        const float* __restrict__ b,
        float* __restrict__ out, int N) {
    const int wv = threadIdx.x >> 6;
    const int l  = threadIdx.x & 63;
    const int g  = l >> 4, q = l & 15;
    const int d  = blockIdx.x * 4 + wv;
    if (d >= N) return;
    const int beg = rowptr[d], end = rowptr[d + 1];
    const int cb = q * 8;
    const float4 xra = *(const float4*)&xr[(size_t)d * OUT_C + cb];
    const float4 xrb = *(const float4*)&xr[(size_t)d * OUT_C + cb + 4];
    float4 a6a = *(const float4*)&att[cb];
    float4 a6b = *(const float4*)&att[cb + 4];
    float4 a4a, a4b;
    a4a.x = 0.4f * a6a.x; a4a.y = 0.4f * a6a.y; a4a.z = 0.4f * a6a.z; a4a.w = 0.4f * a6a.w;
    a4b.x = 0.4f * a6b.x; a4b.y = 0.4f * a6b.y; a4b.z = 0.4f * a6b.z; a4b.w = 0.4f * a6b.w;
    a6a.x *= 0.6f; a6a.y *= 0.6f; a6a.z *= 0.6f; a6a.w *= 0.6f;
    a6b.x *= 0.6f; a6b.y *= 0.6f; a6b.z *= 0.6f; a6b.w *= 0.6f;
    float m = -1e30f, ls = 0.f;
    float4 acca = {0.f,0.f,0.f,0.f}, accb = {0.f,0.f,0.f,0.f};
    for (int c0 = beg; c0 < end; c0 += 16) {
        int sA[4];
#pragma unroll
        for (int u = 0; u < 4; ++u) {
            int j = c0 + 4 * u + g;
            sA[u] = gsrc[min(j, end - 1)];
        }
        uint4 w[4];
#pragma unroll
        for (int u = 0; u < 4; ++u)
            w[u] = *(const uint4*)&xlb[(size_t)sA[u] * OUT_C + cb];
        float f[4];
        float4 va[4], vb[4];
#pragma unroll
        for (int u = 0; u < 4; ++u) {
            float2 c01 = bf2f2(w[u].x), c23 = bf2f2(w[u].y);
            float2 c45 = bf2f2(w[u].z), c67 = bf2f2(w[u].w);
            va[u] = make_float4(c01.x, c01.y, c23.x, c23.y);
            vb[u] = make_float4(c45.x, c45.y, c67.x, c67.y);
            float p = 0.f, t;
            t = va[u].x + xra.x; p = fmaf(a6a.x, t, fmaf(a4a.x, fabsf(t), p));
            t = va[u].y + xra.y; p = fmaf(a6a.y, t, fmaf(a4a.y, fabsf(t), p));
            t = va[u].z + xra.z; p = fmaf(a6a.z, t, fmaf(a4a.z, fabsf(t), p));
            t = va[u].w + xra.w; p = fmaf(a6a.w, t, fmaf(a4a.w, fabsf(t), p));
            t = vb[u].x + xrb.x; p = fmaf(a6b.x, t, fmaf(a4b.x, fabsf(t), p));
            t = vb[u].y + xrb.y; p = fmaf(a6b.y, t, fmaf(a4b.y, fabsf(t), p));
            t = vb[u].z + xrb.z; p = fmaf(a6b.z, t, fmaf(a4b.z, fabsf(t), p));
            t = vb[u].w + xrb.w; p = fmaf(a6b.w, t, fmaf(a4b.w, fabsf(t), p));
            // full-row reduce within 16-lane group
            p += __shfl_xor(p, 1, 64);
            p += __shfl_xor(p, 2, 64);
            p += __shfl_xor(p, 4, 64);
            p += __shfl_xor(p, 8, 64);
            f[u] = (c0 + 4 * u + g < end) ? p : -1e30f;
        }
        float bm = fmaxf(fmaxf(f[0], f[1]), fmaxf(f[2], f[3]));
        float nm = fmaxf(m, bm);
        float fc = __expf(m - nm);
        ls *= fc;
        acca.x *= fc; acca.y *= fc; acca.z *= fc; acca.w *= fc;
        accb.x *= fc; accb.y *= fc; accb.z *= fc; accb.w *= fc;
#pragma unroll
        for (int u = 0; u < 4; ++u) {
            float wgt = __expf(f[u] - nm);
            ls += wgt;
            acca.x = fmaf(wgt, va[u].x, acca.x);
            acca.y = fmaf(wgt, va[u].y, acca.y);
            acca.z = fmaf(wgt, va[u].z, acca.z);
            acca.w = fmaf(wgt, va[u].w, acca.w);
            accb.x = fmaf(wgt, vb[u].x, accb.x);
            accb.y = fmaf(wgt, vb[u].y, accb.y);
            accb.z = fmaf(wgt, vb[u].z, accb.z);
            accb.w = fmaf(wgt, vb[u].w, accb.w);
        }
        m = nm;
    }
#pragma unroll
    for (int o = 16; o <= 32; o <<= 1) {
        float mo = __shfl_xor(m, o, 64);
        float lo = __shfl_xor(ls, o, 64);
        float ax = __shfl_xor(acca.x, o, 64), ay = __shfl_xor(acca.y, o, 64);
        float az = __shfl_xor(acca.z, o, 64), aw = __shfl_xor(acca.w, o, 64);
        float bx = __shfl_xor(accb.x, o, 64), by = __shfl_xor(accb.y, o, 64);
        float bz = __shfl_xor(accb.z, o, 64), bw = __shfl_xor(accb.w, o, 64);
        float nm = fmaxf(m, mo);
        float fs = __expf(m - nm), fo = __expf(mo - nm);
        ls = ls * fs + lo * fo;
        acca.x = acca.x * fs + ax * fo; acca.y = acca.y * fs + ay * fo;
        acca.z = acca.z * fs + az * fo; acca.w = acca.w * fs + aw * fo;
        accb.x = accb.x * fs + bx * fo; accb.y = accb.y * fs + by * fo;
        accb.z = accb.z * fs + bz * fo; accb.w = accb.w * fs + bw * fo;
        m = nm;
    }
    if (g == 0) {
        float inv = (ls > 0.f) ? 1.f / ls : 0.f;
        const float4 b4a = *(const float4*)&b[cb];
        const float4 b4b = *(const float4*)&b[cb + 4];
        float4 o1, o2;
        o1.x = acca.x * inv + b4a.x; o1.y = acca.y * inv + b4a.y;
        o1.z = acca.z * inv + b4a.z; o1.w = acca.w * inv + b4a.w;
        o2.x = accb.x * inv + b4b.x; o2.y = accb.y * inv + b4b.y;
        o2.z = accb.z * inv + b4b.z; o2.w = accb.w * inv + b4b.w;
        *(float4*)&out[(size_t)d * OUT_C + cb]     = o1;
        *(float4*)&out[(size_t)d * OUT_C + cb + 4] = o2;
    }
}

extern "C" void kernel_launch(void* const* d_in, const int* in_sizes, int n_in,
                              void* d_out, int out_size, void* d_ws, size_t ws_size,
                              hipStream_t stream) {
    const float* x    = (const float*)d_in[0];
    const int*   ei   = (const int*)d_in[1];
    const float* W1l  = (const float*)d_in[2];
    const float* W1r  = (const float*)d_in[3];
    const float* att1 = (const float*)d_in[4];
    const float* b1   = (const float*)d_in[5];
    const float* W2l  = (const float*)d_in[6];
    const float* W2r  = (const float*)d_in[7];
    const float* att2 = (const float*)d_in[8];
    const float* b2   = (const float*)d_in[9];

    const int N = in_sizes[0] / IN_C;
    const int E = in_sizes[1] / 2;
    const int* src = ei;
    const int* dst = ei + E;

    // workspace layout
    float* ws = (float*)d_ws;
    size_t o = 0;
    ushort_t* xlb = (ushort_t*)(ws + o); o += (size_t)N * IN_C / 2;  // bf16 x@Wl / h@W2l
    float* xr   = ws + o; o += (size_t)N * IN_C;   // x@Wr (layer1) / h@W2r (layer2)
    float* hbuf = ws + o; o += (size_t)N * IN_C;   // layer1 output h (post ELU, f32)
    int* iws    = (int*)(ws + o);
    int* rowptr = iws;                    // N+1
    int* cnt    = iws + (N + 1);          // N   (cnt+cursor adjacent: one memset)
    int* cursor = iws + (N + 1) + N;      // N
    int* part   = iws + (N + 1) + 2 * N;  // <=1024 block partials
    int* gsrc   = iws + (N + 1) + 2 * N + 1024;  // E  (CSR-ordered source ids)

    hipMemsetAsync(cnt, 0, (size_t)2 * N * 4, stream);   // cnt + cursor

    const int B = 256;
    const int nb = (N + 255) / 256;   // scan blocks (196 <= 1024)
    // ---- CSR by dst (shared by both layers) ----
    hist_kernel<<<(E + B - 1) / B, B, 0, stream>>>(dst, cnt, E);
    scan_block_sums<<<nb, 256, 0, stream>>>(cnt, part, N);
    scan_part_excl<<<1, 1024, 0, stream>>>(part, nb);
    scan_final<<<nb, 256, 0, stream>>>(cnt, part, rowptr, N);
    scatter_csr<<<(E + B - 1) / B, B, 0, stream>>>(src, dst, rowptr, cursor, gsrc, E);

    // ---- layer 1 ----
    transform_dual<<<(N + TROWS - 1) / TROWS, 256, 0, stream>>>(x, W1l, W1r, xlb, xr, N);
    node_fused1<<<(N + 3) / 4, 256, 0, stream>>>(xlb, xr, att1, rowptr, gsrc, b1, hbuf, N);

    // ---- layer 2 ----
    transform_dual<<<(N + TROWS - 1) / TROWS, 256, 0, stream>>>(hbuf, W2l, W2r, xlb, xr, N);
    node_fused2<<<(N + 3) / 4, 256, 0, stream>>>(xlb, xr, att2, rowptr, gsrc, b2, (float*)d_out, N);
}

// Round 10
// 320.542 us; speedup vs baseline: 1.2534x; 1.2534x over previous
//
#include <hip/hip_runtime.h>
#include <math.h>

#define IN_C 128
#define HID 32
#define HEADS 4
#define OUT_C 128
#define NEG_SLOPE 0.2f

typedef unsigned int uint_t;
typedef unsigned short ushort_t;
typedef _Float16 half8 __attribute__((ext_vector_type(8)));
typedef float floatx4 __attribute__((ext_vector_type(4)));

// f32 -> bf16 round-to-nearest-even
__device__ __forceinline__ ushort_t f2bf(float f) {
    uint_t u = __float_as_uint(f);
    u = (u + 0x7fffu + ((u >> 16) & 1u)) >> 16;
    return (ushort_t)u;
}
// one uint = 2 bf16 channels -> 2 floats (low ushort = lower channel)
__device__ __forceinline__ float2 bf2f2(uint_t u) {
    float2 r;
    r.x = __uint_as_float(u << 16);
    r.y = __uint_as_float(u & 0xffff0000u);
    return r;
}

// ---------- MFMA dual transform: outl(bf16) = x@Wl, outr(f32) = x@Wr ----------
// One block = 4 waves; wave w owns 64 output cols: w0/w1 -> Wl cols 0-63/64-127,
// w2/w3 -> Wr cols 0-63/64-127. B-fragments (4 tiles x 4 ksteps) live in VGPRs
// for the whole kernel; grid-stride over 16-row strips.
#define XPAD 136   // f16 row stride: 272B -> 4-bank shift/row -> 2-way (free)
__global__ __launch_bounds__(256) void transform_mfma(
        const float* __restrict__ x,
        const float* __restrict__ Wl,
        const float* __restrict__ Wr,
        ushort_t* __restrict__ outl,
        float* __restrict__ outr, int n) {
    __shared__ _Float16 xs[16 * XPAD + 8];
    const int tid = threadIdx.x;
    const int wv = tid >> 6;
    const int l  = tid & 63;
    const int lm = l & 15;            // m (A) / n (B) / col (C)
    const int quad = l >> 4;          // k-quad selector
    const int kb = quad * 8;

    // ---- preload B fragments for this wave's 64 cols (once per block) ----
    const float* Wsel = (wv < 2) ? Wl : Wr;
    const int nbase = (wv & 1) * 64;
    half8 bw[4][4];
#pragma unroll
    for (int t = 0; t < 4; ++t) {
        const int ncol = nbase + t * 16 + lm;
#pragma unroll
        for (int K = 0; K < 4; ++K) {
            const int k0 = K * 32 + kb;
            half8 h;
#pragma unroll
            for (int j = 0; j < 8; ++j)
                h[j] = (_Float16)Wsel[(size_t)(k0 + j) * IN_C + ncol];
            bw[t][K] = h;
        }
    }

    const int nStrips = (n + 15) >> 4;
    for (int s = blockIdx.x; s < nStrips; s += gridDim.x) {
        const int row0 = s * 16;
        __syncthreads();   // previous iteration's A-frag reads done
        // stage 16x128 f32 -> f16 LDS (each thread: 1 row-segment of 8)
        {
            const int srow = tid >> 4;
            const int sc = (tid & 15) * 8;
            const int grow = row0 + srow;
            float4 v0 = make_float4(0.f, 0.f, 0.f, 0.f);
            float4 v1 = make_float4(0.f, 0.f, 0.f, 0.f);
            if (grow < n) {
                v0 = *(const float4*)&x[(size_t)grow * IN_C + sc];
                v1 = *(const float4*)&x[(size_t)grow * IN_C + sc + 4];
            }
            half8 h;
            h[0] = (_Float16)v0.x; h[1] = (_Float16)v0.y;
            h[2] = (_Float16)v0.z; h[3] = (_Float16)v0.w;
            h[4] = (_Float16)v1.x; h[5] = (_Float16)v1.y;
            h[6] = (_Float16)v1.z; h[7] = (_Float16)v1.w;
            *(half8*)&xs[srow * XPAD + sc] = h;
        }
        __syncthreads();
        // A fragments: lane lm -> row lm, k = K*32 + kb
        half8 af[4];
#pragma unroll
        for (int K = 0; K < 4; ++K)
            af[K] = *(half8*)&xs[lm * XPAD + K * 32 + kb];
        floatx4 acc[4];
#pragma unroll
        for (int t = 0; t < 4; ++t) acc[t] = (floatx4){0.f, 0.f, 0.f, 0.f};
#pragma unroll
        for (int t = 0; t < 4; ++t)
#pragma unroll
            for (int K = 0; K < 4; ++K)
                acc[t] = __builtin_amdgcn_mfma_f32_16x16x32_f16(af[K], bw[t][K], acc[t], 0, 0, 0);
        // store: C layout col=lm, row = quad*4 + r
#pragma unroll
        for (int t = 0; t < 4; ++t) {
            const int col = nbase + t * 16 + lm;
#pragma unroll
            for (int r = 0; r < 4; ++r) {
                const int row = row0 + quad * 4 + r;
                if (row < n) {
                    if (wv < 2) outl[(size_t)row * IN_C + col] = f2bf(acc[t][r]);
                    else        outr[(size_t)row * IN_C + col] = acc[t][r];
                }
            }
        }
    }
}

// ---------- CSR build ----------
__global__ void hist_kernel(const int* __restrict__ dst, int* __restrict__ cnt, int E) {
    int e = blockIdx.x * blockDim.x + threadIdx.x;
    if (e < E) atomicAdd(&cnt[dst[e]], 1);
}

__global__ void scan_block_sums(const int* __restrict__ cnt, int* __restrict__ part, int n) {
    __shared__ int sdata[256];
    int t = threadIdx.x;
    int i = blockIdx.x * 256 + t;
    sdata[t] = (i < n) ? cnt[i] : 0;
    __syncthreads();
    for (int o = 128; o >= 1; o >>= 1) {
        if (t < o) sdata[t] += sdata[t + o];
        __syncthreads();
    }
    if (t == 0) part[blockIdx.x] = sdata[0];
}

__global__ void scan_part_excl(int* __restrict__ part, int nb) {  // single block
    __shared__ int buf[1024];
    int t = threadIdx.x;
    int v = (t < nb) ? part[t] : 0;
    buf[t] = v;
    __syncthreads();
    for (int o = 1; o < 1024; o <<= 1) {
        int a = (t >= o) ? buf[t - o] : 0;
        __syncthreads();
        buf[t] += a;
        __syncthreads();
    }
    if (t < nb) part[t] = buf[t] - v;   // exclusive
}

__global__ void scan_final(const int* __restrict__ cnt, const int* __restrict__ part,
                           int* __restrict__ rowptr, int n) {
    __shared__ int buf[256];
    int t = threadIdx.x;
    int i = blockIdx.x * 256 + t;
    int v = (i < n) ? cnt[i] : 0;
    buf[t] = v;
    __syncthreads();
    for (int o = 1; o < 256; o <<= 1) {
        int a = (t >= o) ? buf[t - o] : 0;
        __syncthreads();
        buf[t] += a;
        __syncthreads();
    }
    int excl = part[blockIdx.x] + buf[t] - v;
    if (i < n) rowptr[i] = excl;
    if (i == n - 1) rowptr[n] = excl + v;
}

__global__ void scatter_csr(const int* __restrict__ src,
                            const int* __restrict__ dst,
                            const int* __restrict__ rowptr,
                            int* __restrict__ cursor,
                            int* __restrict__ gsrc, int E) {
    int e = blockIdx.x * blockDim.x + threadIdx.x;
    if (e >= E) return;
    int d = dst[e];
    int pos = atomicAdd(&cursor[d], 1);
    gsrc[rowptr[d] + pos] = src[e];
}

// ---------- fused kernels: 16-lane group per edge, 4 edges/wave ----------
// BRANCH-FREE chunk loop; loads batched (4 gsrc, then 4 rows).

// layer 1: 4 heads x 32ch; head of lane = q>>2; reduce within 4 lanes.
__global__ __launch_bounds__(256) void node_fused1(
        const ushort_t* __restrict__ xlb,
        const float* __restrict__ xr,
        const float* __restrict__ att,
        const int* __restrict__ rowptr,
        const int* __restrict__ gsrc,
        const float* __restrict__ b,
        float* __restrict__ hout, int N) {
    const int wv = threadIdx.x >> 6;
    const int l  = threadIdx.x & 63;
    const int g  = l >> 4, q = l & 15;
    const int d  = blockIdx.x * 4 + wv;
    if (d >= N) return;
    const int beg = rowptr[d], end = rowptr[d + 1];
    const int cb = q * 8;
    const float4 xra = *(const float4*)&xr[(size_t)d * IN_C + cb];
    const float4 xrb = *(const float4*)&xr[(size_t)d * IN_C + cb + 4];
    float4 a6a = *(const float4*)&att[cb];
    float4 a6b = *(const float4*)&att[cb + 4];
    float4 a4a, a4b;
    a4a.x = 0.4f * a6a.x; a4a.y = 0.4f * a6a.y; a4a.z = 0.4f * a6a.z; a4a.w = 0.4f * a6a.w;
    a4b.x = 0.4f * a6b.x; a4b.y = 0.4f * a6b.y; a4b.z = 0.4f * a6b.z; a4b.w = 0.4f * a6b.w;
    a6a.x *= 0.6f; a6a.y *= 0.6f; a6a.z *= 0.6f; a6a.w *= 0.6f;
    a6b.x *= 0.6f; a6b.y *= 0.6f; a6b.z *= 0.6f; a6b.w *= 0.6f;
    float m = -1e30f, ls = 0.f;
    float4 acca = {0.f,0.f,0.f,0.f}, accb = {0.f,0.f,0.f,0.f};
    for (int c0 = beg; c0 < end; c0 += 16) {
        int sA[4];
#pragma unroll
        for (int u = 0; u < 4; ++u) {
            int j = c0 + 4 * u + g;
            sA[u] = gsrc[min(j, end - 1)];
        }
        uint4 w[4];
#pragma unroll
        for (int u = 0; u < 4; ++u)
            w[u] = *(const uint4*)&xlb[(size_t)sA[u] * IN_C + cb];
        float f[4];
        float4 va[4], vb[4];
#pragma unroll
        for (int u = 0; u < 4; ++u) {
            float2 c01 = bf2f2(w[u].x), c23 = bf2f2(w[u].y);
            float2 c45 = bf2f2(w[u].z), c67 = bf2f2(w[u].w);
            va[u] = make_float4(c01.x, c01.y, c23.x, c23.y);
            vb[u] = make_float4(c45.x, c45.y, c67.x, c67.y);
            float p = 0.f, t;
            t = va[u].x + xra.x; p = fmaf(a6a.x, t, fmaf(a4a.x, fabsf(t), p));
            t = va[u].y + xra.y; p = fmaf(a6a.y, t, fmaf(a4a.y, fabsf(t), p));
            t = va[u].z + xra.z; p = fmaf(a6a.z, t, fmaf(a4a.z, fabsf(t), p));
            t = va[u].w + xra.w; p = fmaf(a6a.w, t, fmaf(a4a.w, fabsf(t), p));
            t = vb[u].x + xrb.x; p = fmaf(a6b.x, t, fmaf(a4b.x, fabsf(t), p));
            t = vb[u].y + xrb.y; p = fmaf(a6b.y, t, fmaf(a4b.y, fabsf(t), p));
            t = vb[u].z + xrb.z; p = fmaf(a6b.z, t, fmaf(a4b.z, fabsf(t), p));
            t = vb[u].w + xrb.w; p = fmaf(a6b.w, t, fmaf(a4b.w, fabsf(t), p));
            p += __shfl_xor(p, 1, 64);
            p += __shfl_xor(p, 2, 64);
            f[u] = (c0 + 4 * u + g < end) ? p : -1e30f;
        }
        float bm = fmaxf(fmaxf(f[0], f[1]), fmaxf(f[2], f[3]));
        float nm = fmaxf(m, bm);
        float fc = __expf(m - nm);
        ls *= fc;
        acca.x *= fc; acca.y *= fc; acca.z *= fc; acca.w *= fc;
        accb.x *= fc; accb.y *= fc; accb.z *= fc; accb.w *= fc;
#pragma unroll
        for (int u = 0; u < 4; ++u) {
            float wgt = __expf(f[u] - nm);
            ls += wgt;
            acca.x = fmaf(wgt, va[u].x, acca.x);
            acca.y = fmaf(wgt, va[u].y, acca.y);
            acca.z = fmaf(wgt, va[u].z, acca.z);
            acca.w = fmaf(wgt, va[u].w, acca.w);
            accb.x = fmaf(wgt, vb[u].x, accb.x);
            accb.y = fmaf(wgt, vb[u].y, accb.y);
            accb.z = fmaf(wgt, vb[u].z, accb.z);
            accb.w = fmaf(wgt, vb[u].w, accb.w);
        }
        m = nm;
    }
#pragma unroll
    for (int o = 16; o <= 32; o <<= 1) {
        float mo = __shfl_xor(m, o, 64);
        float lo = __shfl_xor(ls, o, 64);
        float ax = __shfl_xor(acca.x, o, 64), ay = __shfl_xor(acca.y, o, 64);
        float az = __shfl_xor(acca.z, o, 64), aw = __shfl_xor(acca.w, o, 64);
        float bx = __shfl_xor(accb.x, o, 64), by = __shfl_xor(accb.y, o, 64);
        float bz = __shfl_xor(accb.z, o, 64), bw = __shfl_xor(accb.w, o, 64);
        float nm = fmaxf(m, mo);
        float fs = __expf(m - nm), fo = __expf(mo - nm);
        ls = ls * fs + lo * fo;
        acca.x = acca.x * fs + ax * fo; acca.y = acca.y * fs + ay * fo;
        acca.z = acca.z * fs + az * fo; acca.w = acca.w * fs + aw * fo;
        accb.x = accb.x * fs + bx * fo; accb.y = accb.y * fs + by * fo;
        accb.z = accb.z * fs + bz * fo; accb.w = accb.w * fs + bw * fo;
        m = nm;
    }
    if (g == 0) {
        float inv = (ls > 0.f) ? 1.f / ls : 0.f;
        const float4 b4a = *(const float4*)&b[cb];
        const float4 b4b = *(const float4*)&b[cb + 4];
        float4 o1, o2;
        o1.x = acca.x * inv + b4a.x; o1.y = acca.y * inv + b4a.y;
        o1.z = acca.z * inv + b4a.z; o1.w = acca.w * inv + b4a.w;
        o2.x = accb.x * inv + b4b.x; o2.y = accb.y * inv + b4b.y;
        o2.z = accb.z * inv + b4b.z; o2.w = accb.w * inv + b4b.w;
        o1.x = (o1.x > 0.f) ? o1.x : expm1f(o1.x);
        o1.y = (o1.y > 0.f) ? o1.y : expm1f(o1.y);
        o1.z = (o1.z > 0.f) ? o1.z : expm1f(o1.z);
        o1.w = (o1.w > 0.f) ? o1.w : expm1f(o1.w);
        o2.x = (o2.x > 0.f) ? o2.x : expm1f(o2.x);
        o2.y = (o2.y > 0.f) ? o2.y : expm1f(o2.y);
        o2.z = (o2.z > 0.f) ? o2.z : expm1f(o2.z);
        o2.w = (o2.w > 0.f) ? o2.w : expm1f(o2.w);
        *(float4*)&hout[(size_t)d * IN_C + cb]     = o1;
        *(float4*)&hout[(size_t)d * IN_C + cb + 4] = o2;
    }
}

// layer 2: single head x 128ch; reduce within all 16 lanes of the group.
__global__ __launch_bounds__(256) void node_fused2(
        const ushort_t* __restrict__ xlb,
        const float* __restrict__ xr,
        const float* __restrict__ att,
        const int* __restrict__ rowptr,
        const int* __restrict__ gsrc,
        const float* __restrict__ b,
        float* __restrict__ out, int N) {
    const int wv = threadIdx.x >> 6;
    const int l  = threadIdx.x & 63;
    const int g  = l >> 4, q = l & 15;
    const int d  = blockIdx.x * 4 + wv;
    if (d >= N) return;
    const int beg = rowptr[d], end = rowptr[d + 1];
    const int cb = q * 8;
    const float4 xra = *(const float4*)&xr[(size_t)d * OUT_C + cb];
    const float4 xrb = *(const float4*)&xr[(size_t)d * OUT_C + cb + 4];
    float4 a6a = *(const float4*)&att[cb];
    float4 a6b = *(const float4*)&att[cb + 4];
    float4 a4a, a4b;
    a4a.x = 0.4f * a6a.x; a4a.y = 0.4f * a6a.y; a4a.z = 0.4f * a6a.z; a4a.w = 0.4f * a6a.w;
    a4b.x = 0.4f * a6b.x; a4b.y = 0.4f * a6b.y; a4b.z = 0.4f * a6b.z; a4b.w = 0.4f * a6b.w;
    a6a.x *= 0.6f; a6a.y *= 0.6f; a6a.z *= 0.6f; a6a.w *= 0.6f;
    a6b.x *= 0.6f; a6b.y *= 0.6f; a6b.z *= 0.6f; a6b.w *= 0.6f;
    float m = -1e30f, ls = 0.f;
    float4 acca = {0.f,0.f,0.f,0.f}, accb = {0.f,0.f,0.f,0.f};
    for (int c0 = beg; c0 < end; c0 += 16) {
        int sA[4];
#pragma unroll
        for (int u = 0; u < 4; ++u) {
            int j = c0 + 4 * u + g;
            sA[u] = gsrc[min(j, end - 1)];
        }
        uint4 w[4];
#pragma unroll
        for (int u = 0; u < 4; ++u)
            w[u] = *(const uint4*)&xlb[(size_t)sA[u] * OUT_C + cb];
        float f[4];
        float4 va[4], vb[4];
#pragma unroll
        for (int u = 0; u < 4; ++u) {
            float2 c01 = bf2f2(w[u].x), c23 = bf2f2(w[u].y);
            float2 c45 = bf2f2(w[u].z), c67 = bf2f2(w[u].w);
            va[u] = make_float4(c01.x, c01.y, c23.x, c23.y);
            vb[u] = make_float4(c45.x, c45.y, c67.x, c67.y);
            float p = 0.f, t;
            t = va[u].x + xra.x; p = fmaf(a6a.x, t, fmaf(a4a.x, fabsf(t), p));
            t = va[u].y + xra.y; p = fmaf(a6a.y, t, fmaf(a4a.y, fabsf(t), p));
            t = va[u].z + xra.z; p = fmaf(a6a.z, t, fmaf(a4a.z, fabsf(t), p));
            t = va[u].w + xra.w; p = fmaf(a6a.w, t, fmaf(a4a.w, fabsf(t), p));
            t = vb[u].x + xrb.x; p = fmaf(a6b.x, t, fmaf(a4b.x, fabsf(t), p));
            t = vb[u].y + xrb.y; p = fmaf(a6b.y, t, fmaf(a4b.y, fabsf(t), p));
            t = vb[u].z + xrb.z; p = fmaf(a6b.z, t, fmaf(a4b.z, fabsf(t), p));
            t = vb[u].w + xrb.w; p = fmaf(a6b.w, t, fmaf(a4b.w, fabsf(t), p));
            p += __shfl_xor(p, 1, 64);
            p += __shfl_xor(p, 2, 64);
            p += __shfl_xor(p, 4, 64);
            p += __shfl_xor(p, 8, 64);
            f[u] = (c0 + 4 * u + g < end) ? p : -1e30f;
        }
        float bm = fmaxf(fmaxf(f[0], f[1]), fmaxf(f[2], f[3]));
        float nm = fmaxf(m, bm);
        float fc = __expf(m - nm);
        ls *= fc;
        acca.x *= fc; acca.y *= fc; acca.z *= fc; acca.w *= fc;
        accb.x *= fc; accb.y *= fc; accb.z *= fc; accb.w *= fc;
#pragma unroll
        for (int u = 0; u < 4; ++u) {
            float wgt = __expf(f[u] - nm);
            ls += wgt;
            acca.x = fmaf(wgt, va[u].x, acca.x);
            acca.y = fmaf(wgt, va[u].y, acca.y);
            acca.z = fmaf(wgt, va[u].z, acca.z);
            acca.w = fmaf(wgt, va[u].w, acca.w);
            accb.x = fmaf(wgt, vb[u].x, accb.x);
            accb.y = fmaf(wgt, vb[u].y, accb.y);
            accb.z = fmaf(wgt, vb[u].z, accb.z);
            accb.w = fmaf(wgt, vb[u].w, accb.w);
        }
        m = nm;
    }
#pragma unroll
    for (int o = 16; o <= 32; o <<= 1) {
        float mo = __shfl_xor(m, o, 64);
        float lo = __shfl_xor(ls, o, 64);
        float ax = __shfl_xor(acca.x, o, 64), ay = __shfl_xor(acca.y, o, 64);
        float az = __shfl_xor(acca.z, o, 64), aw = __shfl_xor(acca.w, o, 64);
        float bx = __shfl_xor(accb.x, o, 64), by = __shfl_xor(accb.y, o, 64);
        float bz = __shfl_xor(accb.z, o, 64), bw = __shfl_xor(accb.w, o, 64);
        float nm = fmaxf(m, mo);
        float fs = __expf(m - nm), fo = __expf(mo - nm);
        ls = ls * fs + lo * fo;
        acca.x = acca.x * fs + ax * fo; acca.y = acca.y * fs + ay * fo;
        acca.z = acca.z * fs + az * fo; acca.w = acca.w * fs + aw * fo;
        accb.x = accb.x * fs + bx * fo; accb.y = accb.y * fs + by * fo;
        accb.z = accb.z * fs + bz * fo; accb.w = accb.w * fs + bw * fo;
        m = nm;
    }
    if (g == 0) {
        float inv = (ls > 0.f) ? 1.f / ls : 0.f;
        const float4 b4a = *(const float4*)&b[cb];
        const float4 b4b = *(const float4*)&b[cb + 4];
        float4 o1, o2;
        o1.x = acca.x * inv + b4a.x; o1.y = acca.y * inv + b4a.y;
        o1.z = acca.z * inv + b4a.z; o1.w = acca.w * inv + b4a.w;
        o2.x = accb.x * inv + b4b.x; o2.y = accb.y * inv + b4b.y;
        o2.z = accb.z * inv + b4b.z; o2.w = accb.w * inv + b4b.w;
        *(float4*)&out[(size_t)d * OUT_C + cb]     = o1;
        *(float4*)&out[(size_t)d * OUT_C + cb + 4] = o2;
    }
}

extern "C" void kernel_launch(void* const* d_in, const int* in_sizes, int n_in,
                              void* d_out, int out_size, void* d_ws, size_t ws_size,
                              hipStream_t stream) {
    const float* x    = (const float*)d_in[0];
    const int*   ei   = (const int*)d_in[1];
    const float* W1l  = (const float*)d_in[2];
    const float* W1r  = (const float*)d_in[3];
    const float* att1 = (const float*)d_in[4];
    const float* b1   = (const float*)d_in[5];
    const float* W2l  = (const float*)d_in[6];
    const float* W2r  = (const float*)d_in[7];
    const float* att2 = (const float*)d_in[8];
    const float* b2   = (const float*)d_in[9];

    const int N = in_sizes[0] / IN_C;
    const int E = in_sizes[1] / 2;
    const int* src = ei;
    const int* dst = ei + E;

    // workspace layout
    float* ws = (float*)d_ws;
    size_t o = 0;
    ushort_t* xlb = (ushort_t*)(ws + o); o += (size_t)N * IN_C / 2;  // bf16 x@Wl / h@W2l
    float* xr   = ws + o; o += (size_t)N * IN_C;   // x@Wr (layer1) / h@W2r (layer2)
    float* hbuf = ws + o; o += (size_t)N * IN_C;   // layer1 output h (post ELU, f32)
    int* iws    = (int*)(ws + o);
    int* rowptr = iws;                    // N+1
    int* cnt    = iws + (N + 1);          // N   (cnt+cursor adjacent: one memset)
    int* cursor = iws + (N + 1) + N;      // N
    int* part   = iws + (N + 1) + 2 * N;  // <=1024 block partials
    int* gsrc   = iws + (N + 1) + 2 * N + 1024;  // E  (CSR-ordered source ids)

    hipMemsetAsync(cnt, 0, (size_t)2 * N * 4, stream);   // cnt + cursor

    const int B = 256;
    const int nb = (N + 255) / 256;   // scan blocks (196 <= 1024)
    // ---- CSR by dst (shared by both layers) ----
    hist_kernel<<<(E + B - 1) / B, B, 0, stream>>>(dst, cnt, E);
    scan_block_sums<<<nb, 256, 0, stream>>>(cnt, part, N);
    scan_part_excl<<<1, 1024, 0, stream>>>(part, nb);
    scan_final<<<nb, 256, 0, stream>>>(cnt, part, rowptr, N);
    scatter_csr<<<(E + B - 1) / B, B, 0, stream>>>(src, dst, rowptr, cursor, gsrc, E);

    // ---- layer 1 ----
    transform_mfma<<<512, 256, 0, stream>>>(x, W1l, W1r, xlb, xr, N);
    node_fused1<<<(N + 3) / 4, 256, 0, stream>>>(xlb, xr, att1, rowptr, gsrc, b1, hbuf, N);

    // ---- layer 2 ----
    transform_mfma<<<512, 256, 0, stream>>>(hbuf, W2l, W2r, xlb, xr, N);
    node_fused2<<<(N + 3) / 4, 256, 0, stream>>>(xlb, xr, att2, rowptr, gsrc, b2, (float*)d_out, N);
}